// Round 3
// baseline (1283.524 us; speedup 1.0000x reference)
//
#include <hip/hip_runtime.h>
#include <hip/hip_bf16.h>

#define NN 100000
#define NE 800000
#define NCL 10000

__device__ __forceinline__ float bflo(unsigned int u) {  // low bf16 of packed pair
  return __uint_as_float(u << 16);
}
__device__ __forceinline__ float bfhi(unsigned int u) {  // high bf16 of packed pair
  return __uint_as_float(u & 0xffff0000u);
}
__device__ __forceinline__ unsigned short f2bf(float f) {
  unsigned int u = __float_as_uint(f);
  u += 0x7fffu + ((u >> 16) & 1u);
  return (unsigned short)(u >> 16);
}
// pack two floats that are already exactly-representable bf16 values
__device__ __forceinline__ unsigned int packbf_exact(float lo, float hi) {
  return (__float_as_uint(lo) >> 16) | (__float_as_uint(hi) & 0xffff0000u);
}

__global__ __launch_bounds__(256) void zero_kernel(int* p, int n) {
  int i = blockIdx.x * 256 + threadIdx.x;
  if (i < n) p[i] = 0;
}

// ---- CSR build ----
__global__ __launch_bounds__(256) void count_edges_kernel(const int* __restrict__ ei, int* __restrict__ deg) {
  int e = blockIdx.x * 256 + threadIdx.x;
  if (e < NE) atomicAdd(&deg[ei[NE + e]], 1);
}
__global__ __launch_bounds__(256) void count_nodes_kernel(const int* __restrict__ cl, int* __restrict__ cdeg) {
  int n = blockIdx.x * 256 + threadIdx.x;
  if (n < NN) atomicAdd(&cdeg[cl[n]], 1);
}

__global__ __launch_bounds__(1024) void scan_kernel(const int* __restrict__ deg, int* __restrict__ offs,
                                                    int* __restrict__ cursor, int n) {
  __shared__ int lsum[1024];
  int tid = threadIdx.x;
  int chunk = (n + 1023) >> 10;
  int beg = tid * chunk;
  int end = min(beg + chunk, n);
  int s = 0;
  for (int i = beg; i < end; ++i) s += deg[i];
  lsum[tid] = s;
  __syncthreads();
  for (int off = 1; off < 1024; off <<= 1) {
    int v = (tid >= off) ? lsum[tid - off] : 0;
    __syncthreads();
    lsum[tid] += v;
    __syncthreads();
  }
  int run = lsum[tid] - s;  // exclusive prefix
  for (int i = beg; i < end; ++i) {
    offs[i] = run; cursor[i] = run; run += deg[i];
  }
  if (tid == 1023) offs[n] = lsum[1023];
}

__global__ __launch_bounds__(256) void scatter_edges_kernel(const int* __restrict__ ei, int* __restrict__ cursor,
                                                            int* __restrict__ srclist) {
  int e = blockIdx.x * 256 + threadIdx.x;
  if (e < NE) {
    int t = ei[NE + e];
    int p = atomicAdd(&cursor[t], 1);
    srclist[p] = ei[e];
  }
}
__global__ __launch_bounds__(256) void scatter_nodes_kernel(const int* __restrict__ cl, int* __restrict__ ccursor,
                                                            int* __restrict__ nodelist) {
  int n = blockIdx.x * 256 + threadIdx.x;
  if (n < NN) {
    int p = atomicAdd(&ccursor[cl[n]], 1);
    nodelist[p] = n;
  }
}

// ---- MLP: Linear(C->64) + LN + ReLU + Linear(64->C); one wave per node ----
// input: fp32 [N,C] if !INBF (layer 0), bf16 [N,C] if INBF; output bf16 rows at
// stride `outstride` (left half of next layer's concat buffer)
template<int C, bool INBF>
__global__ __launch_bounds__(256) void mlp_kernel(
    const void* __restrict__ xin_v,
    const float* __restrict__ W1,  // [C,64] fp32
    const float* __restrict__ b1, const float* __restrict__ g, const float* __restrict__ be,
    const float* __restrict__ W2,  // [64,C] fp32
    const float* __restrict__ b2,  // [C]
    unsigned short* __restrict__ out, int outstride)
{
  __shared__ float xs[4][C];
  __shared__ float vs[4][64];
  int tid = threadIdx.x;
  int w = tid >> 6, j = tid & 63;
  long node0 = (long)blockIdx.x * 4;
  if constexpr (INBF) {
    const unsigned short* xh = (const unsigned short*)xin_v;
    constexpr int CH = C / 2;  // packed uints per row
    for (int idx = tid; idx < 4 * CH; idx += 256) {
      int ww = idx / CH, cc = idx & (CH - 1);
      unsigned int u = reinterpret_cast<const unsigned int*>(xh + (node0 + ww) * C)[cc];
      xs[ww][2 * cc] = bflo(u);
      xs[ww][2 * cc + 1] = bfhi(u);
    }
  } else {
    const float* xf = (const float*)xin_v;
    constexpr int CQ = C / 4;  // float4 per row
    for (int idx = tid; idx < 4 * CQ; idx += 256) {
      int ww = idx / CQ, cc = idx & (CQ - 1);
      float4 v = reinterpret_cast<const float4*>(xf + (node0 + ww) * C)[cc];
      xs[ww][4 * cc + 0] = v.x;
      xs[ww][4 * cc + 1] = v.y;
      xs[ww][4 * cc + 2] = v.z;
      xs[ww][4 * cc + 3] = v.w;
    }
  }
  __syncthreads();
  // Linear1: t[j] = b1[j] + sum_c x[c]*W1[c][j]
  float a0 = 0.f, a1 = 0.f, a2 = 0.f, a3 = 0.f;
  for (int c = 0; c < C; c += 4) {
    a0 = fmaf(xs[w][c + 0], W1[(c + 0) * 64 + j], a0);
    a1 = fmaf(xs[w][c + 1], W1[(c + 1) * 64 + j], a1);
    a2 = fmaf(xs[w][c + 2], W1[(c + 2) * 64 + j], a2);
    a3 = fmaf(xs[w][c + 3], W1[(c + 3) * 64 + j], a3);
  }
  float t = (a0 + a1) + (a2 + a3) + b1[j];
  // LayerNorm across 64 lanes (H=64)
  float s = t;
  #pragma unroll
  for (int off = 32; off > 0; off >>= 1) s += __shfl_xor(s, off, 64);
  float mu = s * (1.0f / 64.0f);
  float d = t - mu;
  float q = d * d;
  #pragma unroll
  for (int off = 32; off > 0; off >>= 1) q += __shfl_xor(q, off, 64);
  float r = rsqrtf(q * (1.0f / 64.0f) + 1e-5f);
  float v = fmaxf(0.0f, d * r * g[j] + be[j]);
  vs[w][j] = v;
  __syncthreads();
  // Linear2: h[c] = b2[c] + sum_j2 v[j2]*W2[j2][c]
  constexpr int K = C / 64;
  float acc[K];
  #pragma unroll
  for (int k = 0; k < K; ++k) acc[k] = b2[k * 64 + j];
  for (int j2 = 0; j2 < 64; ++j2) {
    float vv = vs[w][j2];
    #pragma unroll
    for (int k = 0; k < K; ++k)
      acc[k] = fmaf(vv, W2[j2 * C + k * 64 + j], acc[k]);
  }
  unsigned short* orow = out + (node0 + w) * outstride;
  #pragma unroll
  for (int k = 0; k < K; ++k) orow[k * 64 + j] = f2bf(acc[k]);
}

// ---- per-target max aggregation over CSR in-edges (bf16 storage) ----
// reads left half (C bf16) of each source row of xnext [N, 2C], writes right half
template<int C>
__global__ __launch_bounds__(256) void aggr_kernel(
    const int* __restrict__ offs, const int* __restrict__ srclist,
    unsigned short* __restrict__ xnext)
{
  constexpr int Q = C / 8;          // uint4 (8 bf16) chunks per half-row
  constexpr int NPB = 256 / Q;      // nodes per block
  int q = threadIdx.x & (Q - 1);
  int ln = threadIdx.x / Q;
  long node = (long)blockIdx.x * NPB + ln;
  int beg = offs[node], end = offs[node + 1];
  float m[8];
  #pragma unroll
  for (int k = 0; k < 8; ++k) m[k] = -3.4e38f;
  for (int e = beg; e < end; ++e) {
    int sidx = srclist[e];
    uint4 u = reinterpret_cast<const uint4*>(xnext + (long)sidx * (2 * C))[q];
    m[0] = fmaxf(m[0], bflo(u.x)); m[1] = fmaxf(m[1], bfhi(u.x));
    m[2] = fmaxf(m[2], bflo(u.y)); m[3] = fmaxf(m[3], bfhi(u.y));
    m[4] = fmaxf(m[4], bflo(u.z)); m[5] = fmaxf(m[5], bfhi(u.z));
    m[6] = fmaxf(m[6], bflo(u.w)); m[7] = fmaxf(m[7], bfhi(u.w));
  }
  if (beg == end) {
    #pragma unroll
    for (int k = 0; k < 8; ++k) m[k] = 0.f;
  }
  uint4 o;
  o.x = packbf_exact(m[0], m[1]);
  o.y = packbf_exact(m[2], m[3]);
  o.z = packbf_exact(m[4], m[5]);
  o.w = packbf_exact(m[6], m[7]);
  reinterpret_cast<uint4*>(xnext + (long)node * (2 * C) + C)[q] = o;
}

// ---- cluster max-pool over CSR node lists: x3 bf16 [N,512] -> pooled fp32 [NC,512] ----
__global__ __launch_bounds__(256) void pool_kernel(
    const int* __restrict__ coffs, const int* __restrict__ nodelist,
    const unsigned short* __restrict__ x3, float* __restrict__ pooled)
{
  int q = threadIdx.x & 63;        // 64 uint4 chunks of 512 bf16
  int lc = threadIdx.x >> 6;       // 4 clusters per block
  long k = (long)blockIdx.x * 4 + lc;
  int beg = coffs[k], end = coffs[k + 1];
  float m[8];
  #pragma unroll
  for (int t = 0; t < 8; ++t) m[t] = -3.4e38f;
  for (int e = beg; e < end; ++e) {
    int n = nodelist[e];
    uint4 u = reinterpret_cast<const uint4*>(x3 + (long)n * 512)[q];
    m[0] = fmaxf(m[0], bflo(u.x)); m[1] = fmaxf(m[1], bfhi(u.x));
    m[2] = fmaxf(m[2], bflo(u.y)); m[3] = fmaxf(m[3], bfhi(u.y));
    m[4] = fmaxf(m[4], bflo(u.z)); m[5] = fmaxf(m[5], bfhi(u.z));
    m[6] = fmaxf(m[6], bflo(u.w)); m[7] = fmaxf(m[7], bfhi(u.w));
  }
  if (beg == end) {
    #pragma unroll
    for (int t = 0; t < 8; ++t) m[t] = 0.f;
  }
  float* orow = pooled + k * 512 + q * 8;
  reinterpret_cast<float4*>(orow)[0] = make_float4(m[0], m[1], m[2], m[3]);
  reinterpret_cast<float4*>(orow)[1] = make_float4(m[4], m[5], m[6], m[7]);
}

// ---- column sum-of-squares (partial per block + atomic) ----
__global__ __launch_bounds__(256) void colnorm_kernel(const float* __restrict__ pooled,
                                                      float* __restrict__ normsq) {
  int tid = threadIdx.x;
  int rows_per = (NCL + gridDim.x - 1) / gridDim.x;
  int r0 = blockIdx.x * rows_per;
  int r1 = min(r0 + rows_per, NCL);
  float s0 = 0.f, s1 = 0.f;
  for (int r = r0; r < r1; ++r) {
    float a = pooled[(long)r * 512 + tid];
    float b = pooled[(long)r * 512 + 256 + tid];
    s0 = fmaf(a, a, s0);
    s1 = fmaf(b, b, s1);
  }
  atomicAdd(&normsq[tid], s0);
  atomicAdd(&normsq[tid + 256], s1);
}

__global__ __launch_bounds__(256) void normalize_kernel(const float* __restrict__ pooled,
                                                        const float* __restrict__ normsq,
                                                        float* __restrict__ out) {
  long idx = (long)blockIdx.x * 256 + threadIdx.x;
  if (idx < (long)NCL * 512) {
    float nv = normsq[idx & 511];
    out[idx] = pooled[idx] * rsqrtf(nv);
  }
}

extern "C" void kernel_launch(void* const* d_in, const int* in_sizes, int n_in,
                              void* d_out, int out_size, void* d_ws, size_t ws_size,
                              hipStream_t stream) {
  const float* x0 = (const float*)d_in[0];     // fp32 [N, 64]
  const int* ei = (const int*)d_in[1];         // int32 [2, E]
  const int* cl = (const int*)d_in[2];         // int32 [N]

  // fp32 weights, used directly from d_in
  const float* W1f[3]; const float* b1f[3]; const float* gf[3];
  const float* bef[3]; const float* W2f[3]; const float* b2f[3];
  for (int i = 0; i < 3; ++i) {
    W1f[i] = (const float*)d_in[3 + 6 * i + 0];
    b1f[i] = (const float*)d_in[3 + 6 * i + 1];
    gf[i]  = (const float*)d_in[3 + 6 * i + 2];
    bef[i] = (const float*)d_in[3 + 6 * i + 3];
    W2f[i] = (const float*)d_in[3 + 6 * i + 4];
    b2f[i] = (const float*)d_in[3 + 6 * i + 5];
  }

  char* ws = (char*)d_ws;
  size_t off = 0;
  auto take = [&](size_t bytes) {
    size_t o = off; off = (off + bytes + 255) & ~(size_t)255; return o;
  };
  // x3 region doubles as x1 (x1 is dead before mlp layer 2 writes x3)
  unsigned short* x3 = (unsigned short*)(ws + take((size_t)NN * 512 * 2));
  unsigned short* x1 = x3;
  unsigned short* x2 = (unsigned short*)(ws + take((size_t)NN * 256 * 2));
  float* pooled = (float*)(ws + take((size_t)NCL * 512 * 4));
  int* zero_base = (int*)(ws + take((size_t)(NN + NCL + 512) * 4));
  int* deg = zero_base;
  int* cdeg = zero_base + NN;
  float* normsq = (float*)(zero_base + NN + NCL);
  int* offs = (int*)(ws + take((size_t)(NN + 1) * 4));
  int* cursor = (int*)(ws + take((size_t)NN * 4));
  int* srclist = (int*)(ws + take((size_t)NE * 4));
  int* coffs = (int*)(ws + take((size_t)(NCL + 1) * 4));
  int* ccursor = (int*)(ws + take((size_t)NCL * 4));
  int* nodelist = (int*)(ws + take((size_t)NN * 4));

  // Workspace guard: bail cleanly if scratch too small (clean absmax signal
  // instead of a memory fault).
  if (off > ws_size) return;

  int zn = NN + NCL + 512;
  zero_kernel<<<(zn + 255) / 256, 256, 0, stream>>>(zero_base, zn);
  count_edges_kernel<<<(NE + 255) / 256, 256, 0, stream>>>(ei, deg);
  count_nodes_kernel<<<(NN + 255) / 256, 256, 0, stream>>>(cl, cdeg);
  scan_kernel<<<1, 1024, 0, stream>>>(deg, offs, cursor, NN);
  scan_kernel<<<1, 1024, 0, stream>>>(cdeg, coffs, ccursor, NCL);
  scatter_edges_kernel<<<(NE + 255) / 256, 256, 0, stream>>>(ei, cursor, srclist);
  scatter_nodes_kernel<<<(NN + 255) / 256, 256, 0, stream>>>(cl, ccursor, nodelist);

  // layer 0: x0(fp32,[N,64]) -> x1[N,128] (bf16)
  mlp_kernel<64, false><<<NN / 4, 256, 0, stream>>>(x0, W1f[0], b1f[0], gf[0], bef[0], W2f[0], b2f[0], x1, 128);
  aggr_kernel<64><<<NN / 32, 256, 0, stream>>>(offs, srclist, x1);
  // layer 1: x1 -> x2[N,256] (bf16)
  mlp_kernel<128, true><<<NN / 4, 256, 0, stream>>>(x1, W1f[1], b1f[1], gf[1], bef[1], W2f[1], b2f[1], x2, 256);
  aggr_kernel<128><<<NN / 16, 256, 0, stream>>>(offs, srclist, x2);
  // layer 2: x2 -> x3[N,512] (bf16; overwrites dead x1 region)
  mlp_kernel<256, true><<<NN / 4, 256, 0, stream>>>(x2, W1f[2], b1f[2], gf[2], bef[2], W2f[2], b2f[2], x3, 512);
  aggr_kernel<256><<<NN / 8, 256, 0, stream>>>(offs, srclist, x3);

  pool_kernel<<<NCL / 4, 256, 0, stream>>>(coffs, nodelist, x3, pooled);
  colnorm_kernel<<<128, 256, 0, stream>>>(pooled, normsq);
  normalize_kernel<<<((long)NCL * 512 + 255) / 256, 256, 0, stream>>>(pooled, normsq, (float*)d_out);
}

// Round 4
// 788.585 us; speedup vs baseline: 1.6276x; 1.6276x over previous
//
#include <hip/hip_runtime.h>
#include <hip/hip_bf16.h>

#define NN 100000
#define NE 800000
#define NCL 10000

typedef __attribute__((ext_vector_type(8))) short short8;
typedef __attribute__((ext_vector_type(4))) float f32x4;

__device__ __forceinline__ float bflo(unsigned int u) {
  return __uint_as_float(u << 16);
}
__device__ __forceinline__ float bfhi(unsigned int u) {
  return __uint_as_float(u & 0xffff0000u);
}
__device__ __forceinline__ unsigned short f2bf(float f) {
  unsigned int u = __float_as_uint(f);
  u += 0x7fffu + ((u >> 16) & 1u);
  return (unsigned short)(u >> 16);
}
__device__ __forceinline__ unsigned int packbf_exact(float lo, float hi) {
  return (__float_as_uint(lo) >> 16) | (__float_as_uint(hi) & 0xffff0000u);
}

__global__ __launch_bounds__(256) void zero_kernel(int* p, int n) {
  int i = blockIdx.x * 256 + threadIdx.x;
  if (i < n) p[i] = 0;
}

// ---- CSR build ----
__global__ __launch_bounds__(256) void count_edges_kernel(const int* __restrict__ ei, int* __restrict__ deg) {
  int e = blockIdx.x * 256 + threadIdx.x;
  if (e < NE) atomicAdd(&deg[ei[NE + e]], 1);
}
__global__ __launch_bounds__(256) void count_nodes_kernel(const int* __restrict__ cl, int* __restrict__ cdeg) {
  int n = blockIdx.x * 256 + threadIdx.x;
  if (n < NN) atomicAdd(&cdeg[cl[n]], 1);
}

__global__ __launch_bounds__(1024) void scan_kernel(const int* __restrict__ deg, int* __restrict__ offs,
                                                    int* __restrict__ cursor, int n) {
  __shared__ int lsum[1024];
  int tid = threadIdx.x;
  int chunk = (n + 1023) >> 10;
  int beg = tid * chunk;
  int end = min(beg + chunk, n);
  int s = 0;
  for (int i = beg; i < end; ++i) s += deg[i];
  lsum[tid] = s;
  __syncthreads();
  for (int off = 1; off < 1024; off <<= 1) {
    int v = (tid >= off) ? lsum[tid - off] : 0;
    __syncthreads();
    lsum[tid] += v;
    __syncthreads();
  }
  int run = lsum[tid] - s;  // exclusive prefix
  for (int i = beg; i < end; ++i) {
    offs[i] = run; cursor[i] = run; run += deg[i];
  }
  if (tid == 1023) offs[n] = lsum[1023];
}

__global__ __launch_bounds__(256) void scatter_edges_kernel(const int* __restrict__ ei, int* __restrict__ cursor,
                                                            int* __restrict__ srclist) {
  int e = blockIdx.x * 256 + threadIdx.x;
  if (e < NE) {
    int t = ei[NE + e];
    int p = atomicAdd(&cursor[t], 1);
    srclist[p] = ei[e];
  }
}
__global__ __launch_bounds__(256) void scatter_nodes_kernel(const int* __restrict__ cl, int* __restrict__ ccursor,
                                                            int* __restrict__ nodelist) {
  int n = blockIdx.x * 256 + threadIdx.x;
  if (n < NN) {
    int p = atomicAdd(&ccursor[cl[n]], 1);
    nodelist[p] = n;
  }
}

// ---- weight prep: fp32 [rows][cols] -> bf16 transposed [cols][rows], once per launch ----
struct WtDesc { const float* src; unsigned short* dst; int rows, cols; };
struct WtPack { WtDesc d[6]; };
__global__ __launch_bounds__(256) void wprep_kernel(WtPack p) {
  long stride = (long)gridDim.x * 256;
  for (int a = 0; a < 6; ++a) {
    int rows = p.d[a].rows, cols = p.d[a].cols, n = rows * cols;
    const float* src = p.d[a].src;
    unsigned short* dst = p.d[a].dst;
    for (long i = (long)blockIdx.x * 256 + threadIdx.x; i < n; i += stride) {
      int r = (int)(i / cols), c = (int)(i % cols);
      dst[(long)c * rows + r] = f2bf(src[(long)r * cols + c]);
    }
  }
}

// ---- MFMA MLP: Linear(C->64) + LN + ReLU + Linear(64->C) ----
// Block = 64 nodes (4 waves x 16). A-layout: A[m=lane&15][k=quad*8+j];
// C/D layout: col=lane&15, row=quad*4+reg (m89/m120-verified).
template<int C, bool INF32>
__global__ __launch_bounds__(256) void mlp_mfma_kernel(
    const void* __restrict__ xin_v,          // fp32 [N,C] or bf16 [N,C]
    const unsigned short* __restrict__ W1T,  // bf16 [64][C]   (W1T[n][c] = W1[c][n])
    const float* __restrict__ b1, const float* __restrict__ g, const float* __restrict__ be,
    const unsigned short* __restrict__ W2T,  // bf16 [C][64]   (W2T[co][j] = W2[j][co])
    const float* __restrict__ b2,            // [C]
    unsigned short* __restrict__ out, int outstride)
{
  constexpr int CP = C + 8;                  // padded LDS row (bf16 elems)
  __shared__ unsigned short xs[64 * CP];
  __shared__ unsigned short ps[64 * 72];
  int tid = threadIdx.x;
  long nb = (long)blockIdx.x * 64;

  // stage X tile -> LDS bf16
  if constexpr (INF32) {
    const float* xf = (const float*)xin_v;
    constexpr int TOT = 64 * (C / 4);
    for (int i = tid; i < TOT; i += 256) {
      int r = i / (C / 4), cc = i % (C / 4);
      long row = nb + r; if (row >= NN) row = NN - 1;
      float4 v = reinterpret_cast<const float4*>(xf + row * C)[cc];
      unsigned int* dst = (unsigned int*)&xs[r * CP + cc * 4];
      dst[0] = (unsigned int)f2bf(v.x) | ((unsigned int)f2bf(v.y) << 16);
      dst[1] = (unsigned int)f2bf(v.z) | ((unsigned int)f2bf(v.w) << 16);
    }
  } else {
    const unsigned short* xh = (const unsigned short*)xin_v;
    constexpr int TOT = 64 * (C / 8);
    for (int i = tid; i < TOT; i += 256) {
      int r = i / (C / 8), cc = i % (C / 8);
      long row = nb + r; if (row >= NN) row = NN - 1;
      uint4 u = reinterpret_cast<const uint4*>(xh + row * C)[cc];
      *reinterpret_cast<uint4*>(&xs[r * CP + cc * 8]) = u;
    }
  }
  __syncthreads();

  int wv = tid >> 6, lane = tid & 63;
  int l15 = lane & 15, q = lane >> 4;
  int mrow = wv * 16;

  // per-lane LN params at n = 16t + l15
  float b1v[4], gv[4], bev[4];
  #pragma unroll
  for (int t = 0; t < 4; ++t) {
    b1v[t] = b1[t * 16 + l15];
    gv[t]  = g[t * 16 + l15];
    bev[t] = be[t * 16 + l15];
  }

  // GEMM1: H1[m][n] = X[m][:] . W1[:][n]
  f32x4 acc[4];
  #pragma unroll
  for (int t = 0; t < 4; ++t) acc[t] = (f32x4){0.f, 0.f, 0.f, 0.f};
  #pragma unroll
  for (int kk = 0; kk < C / 32; ++kk) {
    short8 a = *reinterpret_cast<const short8*>(&xs[(mrow + l15) * CP + kk * 32 + q * 8]);
    #pragma unroll
    for (int t = 0; t < 4; ++t) {
      short8 b = *reinterpret_cast<const short8*>(&W1T[(t * 16 + l15) * C + kk * 32 + q * 8]);
      acc[t] = __builtin_amdgcn_mfma_f32_16x16x32_bf16(a, b, acc[t], 0, 0, 0);
    }
  }

  // epilogue1: +b1, LayerNorm over n (64) per row, ReLU; rows owned: m = q*4+r
  float vout[4][4];  // [t][r]
  #pragma unroll
  for (int r = 0; r < 4; ++r) {
    float h0 = acc[0][r] + b1v[0];
    float h1 = acc[1][r] + b1v[1];
    float h2 = acc[2][r] + b1v[2];
    float h3 = acc[3][r] + b1v[3];
    float s = (h0 + h1) + (h2 + h3);
    s += __shfl_xor(s, 1); s += __shfl_xor(s, 2);
    s += __shfl_xor(s, 4); s += __shfl_xor(s, 8);
    float mu = s * (1.0f / 64.0f);
    float d0 = h0 - mu, d1 = h1 - mu, d2 = h2 - mu, d3 = h3 - mu;
    float qs = (d0 * d0 + d1 * d1) + (d2 * d2 + d3 * d3);
    qs += __shfl_xor(qs, 1); qs += __shfl_xor(qs, 2);
    qs += __shfl_xor(qs, 4); qs += __shfl_xor(qs, 8);
    float rinv = rsqrtf(qs * (1.0f / 64.0f) + 1e-5f);
    vout[0][r] = fmaxf(0.f, d0 * rinv * gv[0] + bev[0]);
    vout[1][r] = fmaxf(0.f, d1 * rinv * gv[1] + bev[1]);
    vout[2][r] = fmaxf(0.f, d2 * rinv * gv[2] + bev[2]);
    vout[3][r] = fmaxf(0.f, d3 * rinv * gv[3] + bev[3]);
  }

  // P -> LDS (C/D layout -> row-major), rows are wave-private so no barrier
  #pragma unroll
  for (int t = 0; t < 4; ++t)
    #pragma unroll
    for (int r = 0; r < 4; ++r)
      ps[(mrow + q * 4 + r) * 72 + t * 16 + l15] = f2bf(vout[t][r]);

  // GEMM2: H2[m][co] = P[m][:] . W2[:][co], K=64
  constexpr int NT2 = C / 16;
  f32x4 acc2[NT2];
  #pragma unroll
  for (int tc = 0; tc < NT2; ++tc) acc2[tc] = (f32x4){0.f, 0.f, 0.f, 0.f};
  #pragma unroll
  for (int s = 0; s < 2; ++s) {
    short8 a = *reinterpret_cast<const short8*>(&ps[(mrow + l15) * 72 + s * 32 + q * 8]);
    #pragma unroll
    for (int tc = 0; tc < NT2; ++tc) {
      short8 b = *reinterpret_cast<const short8*>(&W2T[(tc * 16 + l15) * 64 + s * 32 + q * 8]);
      acc2[tc] = __builtin_amdgcn_mfma_f32_16x16x32_bf16(a, b, acc2[tc], 0, 0, 0);
    }
  }

  // epilogue2: +b2, bf16, store (guarded for tail)
  #pragma unroll
  for (int tc = 0; tc < NT2; ++tc) {
    float bb = b2[tc * 16 + l15];
    #pragma unroll
    for (int r = 0; r < 4; ++r) {
      long node = nb + mrow + q * 4 + r;
      if (node < NN) out[node * (long)outstride + tc * 16 + l15] = f2bf(acc2[tc][r] + bb);
    }
  }
}

// ---- per-target max aggregation over CSR in-edges (bf16 storage) ----
template<int C>
__global__ __launch_bounds__(256) void aggr_kernel(
    const int* __restrict__ offs, const int* __restrict__ srclist,
    unsigned short* __restrict__ xnext)
{
  constexpr int Q = C / 8;
  constexpr int NPB = 256 / Q;
  int q = threadIdx.x & (Q - 1);
  int ln = threadIdx.x / Q;
  long node = (long)blockIdx.x * NPB + ln;
  int beg = offs[node], end = offs[node + 1];
  float m[8];
  #pragma unroll
  for (int k = 0; k < 8; ++k) m[k] = -3.4e38f;
  for (int e = beg; e < end; ++e) {
    int sidx = srclist[e];
    uint4 u = reinterpret_cast<const uint4*>(xnext + (long)sidx * (2 * C))[q];
    m[0] = fmaxf(m[0], bflo(u.x)); m[1] = fmaxf(m[1], bfhi(u.x));
    m[2] = fmaxf(m[2], bflo(u.y)); m[3] = fmaxf(m[3], bfhi(u.y));
    m[4] = fmaxf(m[4], bflo(u.z)); m[5] = fmaxf(m[5], bfhi(u.z));
    m[6] = fmaxf(m[6], bflo(u.w)); m[7] = fmaxf(m[7], bfhi(u.w));
  }
  if (beg == end) {
    #pragma unroll
    for (int k = 0; k < 8; ++k) m[k] = 0.f;
  }
  uint4 o;
  o.x = packbf_exact(m[0], m[1]);
  o.y = packbf_exact(m[2], m[3]);
  o.z = packbf_exact(m[4], m[5]);
  o.w = packbf_exact(m[6], m[7]);
  reinterpret_cast<uint4*>(xnext + (long)node * (2 * C) + C)[q] = o;
}

// ---- cluster max-pool: x3 bf16 [N,512] -> pooled fp32 [NC,512] ----
__global__ __launch_bounds__(256) void pool_kernel(
    const int* __restrict__ coffs, const int* __restrict__ nodelist,
    const unsigned short* __restrict__ x3, float* __restrict__ pooled)
{
  int q = threadIdx.x & 63;
  int lc = threadIdx.x >> 6;
  long k = (long)blockIdx.x * 4 + lc;
  int beg = coffs[k], end = coffs[k + 1];
  float m[8];
  #pragma unroll
  for (int t = 0; t < 8; ++t) m[t] = -3.4e38f;
  for (int e = beg; e < end; ++e) {
    int n = nodelist[e];
    uint4 u = reinterpret_cast<const uint4*>(x3 + (long)n * 512)[q];
    m[0] = fmaxf(m[0], bflo(u.x)); m[1] = fmaxf(m[1], bfhi(u.x));
    m[2] = fmaxf(m[2], bflo(u.y)); m[3] = fmaxf(m[3], bfhi(u.y));
    m[4] = fmaxf(m[4], bflo(u.z)); m[5] = fmaxf(m[5], bfhi(u.z));
    m[6] = fmaxf(m[6], bflo(u.w)); m[7] = fmaxf(m[7], bfhi(u.w));
  }
  if (beg == end) {
    #pragma unroll
    for (int t = 0; t < 8; ++t) m[t] = 0.f;
  }
  float* orow = pooled + k * 512 + q * 8;
  reinterpret_cast<float4*>(orow)[0] = make_float4(m[0], m[1], m[2], m[3]);
  reinterpret_cast<float4*>(orow)[1] = make_float4(m[4], m[5], m[6], m[7]);
}

__global__ __launch_bounds__(256) void colnorm_kernel(const float* __restrict__ pooled,
                                                      float* __restrict__ normsq) {
  int tid = threadIdx.x;
  int rows_per = (NCL + gridDim.x - 1) / gridDim.x;
  int r0 = blockIdx.x * rows_per;
  int r1 = min(r0 + rows_per, NCL);
  float s0 = 0.f, s1 = 0.f;
  for (int r = r0; r < r1; ++r) {
    float a = pooled[(long)r * 512 + tid];
    float b = pooled[(long)r * 512 + 256 + tid];
    s0 = fmaf(a, a, s0);
    s1 = fmaf(b, b, s1);
  }
  atomicAdd(&normsq[tid], s0);
  atomicAdd(&normsq[tid + 256], s1);
}

__global__ __launch_bounds__(256) void normalize_kernel(const float* __restrict__ pooled,
                                                        const float* __restrict__ normsq,
                                                        float* __restrict__ out) {
  long idx = (long)blockIdx.x * 256 + threadIdx.x;
  if (idx < (long)NCL * 512) {
    float nv = normsq[idx & 511];
    out[idx] = pooled[idx] * rsqrtf(nv);
  }
}

extern "C" void kernel_launch(void* const* d_in, const int* in_sizes, int n_in,
                              void* d_out, int out_size, void* d_ws, size_t ws_size,
                              hipStream_t stream) {
  const float* x0 = (const float*)d_in[0];
  const int* ei = (const int*)d_in[1];
  const int* cl = (const int*)d_in[2];

  const float* W1f[3]; const float* b1f[3]; const float* gf[3];
  const float* bef[3]; const float* W2f[3]; const float* b2f[3];
  for (int i = 0; i < 3; ++i) {
    W1f[i] = (const float*)d_in[3 + 6 * i + 0];
    b1f[i] = (const float*)d_in[3 + 6 * i + 1];
    gf[i]  = (const float*)d_in[3 + 6 * i + 2];
    bef[i] = (const float*)d_in[3 + 6 * i + 3];
    W2f[i] = (const float*)d_in[3 + 6 * i + 4];
    b2f[i] = (const float*)d_in[3 + 6 * i + 5];
  }

  char* ws = (char*)d_ws;
  size_t off = 0;
  auto take = [&](size_t bytes) {
    size_t o = off; off = (off + bytes + 255) & ~(size_t)255; return o;
  };
  unsigned short* x3 = (unsigned short*)(ws + take((size_t)NN * 512 * 2));
  unsigned short* x1 = x3;  // x1 dead before x3 written
  unsigned short* x2 = (unsigned short*)(ws + take((size_t)NN * 256 * 2));
  float* pooled = (float*)(ws + take((size_t)NCL * 512 * 4));
  int* zero_base = (int*)(ws + take((size_t)(NN + NCL + 512) * 4));
  int* deg = zero_base;
  int* cdeg = zero_base + NN;
  float* normsq = (float*)(zero_base + NN + NCL);
  int* offs = (int*)(ws + take((size_t)(NN + 1) * 4));
  int* cursor = (int*)(ws + take((size_t)NN * 4));
  int* srclist = (int*)(ws + take((size_t)NE * 4));
  int* coffs = (int*)(ws + take((size_t)(NCL + 1) * 4));
  int* ccursor = (int*)(ws + take((size_t)NCL * 4));
  int* nodelist = (int*)(ws + take((size_t)NN * 4));

  // transposed bf16 weights
  int Cs[3] = {64, 128, 256};
  unsigned short *W1T[3], *W2T[3];
  for (int i = 0; i < 3; ++i) {
    W1T[i] = (unsigned short*)(ws + take((size_t)64 * Cs[i] * 2));
    W2T[i] = (unsigned short*)(ws + take((size_t)Cs[i] * 64 * 2));
  }

  if (off > ws_size) return;  // clean-fail guard

  int zn = NN + NCL + 512;
  zero_kernel<<<(zn + 255) / 256, 256, 0, stream>>>(zero_base, zn);
  count_edges_kernel<<<(NE + 255) / 256, 256, 0, stream>>>(ei, deg);
  count_nodes_kernel<<<(NN + 255) / 256, 256, 0, stream>>>(cl, cdeg);
  scan_kernel<<<1, 1024, 0, stream>>>(deg, offs, cursor, NN);
  scan_kernel<<<1, 1024, 0, stream>>>(cdeg, coffs, ccursor, NCL);
  scatter_edges_kernel<<<(NE + 255) / 256, 256, 0, stream>>>(ei, cursor, srclist);
  scatter_nodes_kernel<<<(NN + 255) / 256, 256, 0, stream>>>(cl, ccursor, nodelist);

  WtPack wp;
  for (int i = 0; i < 3; ++i) {
    wp.d[2 * i + 0] = { W1f[i], W1T[i], Cs[i], 64 };   // [C][64] -> [64][C]
    wp.d[2 * i + 1] = { W2f[i], W2T[i], 64, Cs[i] };   // [64][C] -> [C][64]
  }
  wprep_kernel<<<32, 256, 0, stream>>>(wp);

  int nblk = (NN + 63) / 64;  // 1563
  mlp_mfma_kernel<64, true><<<nblk, 256, 0, stream>>>(
      x0, W1T[0], b1f[0], gf[0], bef[0], W2T[0], b2f[0], x1, 128);
  aggr_kernel<64><<<NN / 32, 256, 0, stream>>>(offs, srclist, x1);
  mlp_mfma_kernel<128, false><<<nblk, 256, 0, stream>>>(
      x1, W1T[1], b1f[1], gf[1], bef[1], W2T[1], b2f[1], x2, 256);
  aggr_kernel<128><<<NN / 16, 256, 0, stream>>>(offs, srclist, x2);
  mlp_mfma_kernel<256, false><<<nblk, 256, 0, stream>>>(
      x2, W1T[2], b1f[2], gf[2], bef[2], W2T[2], b2f[2], x3, 512);
  aggr_kernel<256><<<NN / 8, 256, 0, stream>>>(offs, srclist, x3);

  pool_kernel<<<NCL / 4, 256, 0, stream>>>(coffs, nodelist, x3, pooled);
  colnorm_kernel<<<128, 256, 0, stream>>>(pooled, normsq);
  normalize_kernel<<<((long)NCL * 512 + 255) / 256, 256, 0, stream>>>(pooled, normsq, (float*)d_out);
}

// Round 5
// 564.841 us; speedup vs baseline: 2.2724x; 1.3961x over previous
//
#include <hip/hip_runtime.h>
#include <hip/hip_bf16.h>

#define NN 100000
#define NE 800000
#define NCL 10000

typedef __attribute__((ext_vector_type(8))) short short8;
typedef __attribute__((ext_vector_type(4))) float f32x4;

__device__ __forceinline__ float bflo(unsigned int u) {
  return __uint_as_float(u << 16);
}
__device__ __forceinline__ float bfhi(unsigned int u) {
  return __uint_as_float(u & 0xffff0000u);
}
__device__ __forceinline__ unsigned short f2bf(float f) {
  unsigned int u = __float_as_uint(f);
  u += 0x7fffu + ((u >> 16) & 1u);
  return (unsigned short)(u >> 16);
}
__device__ __forceinline__ unsigned int packbf_exact(float lo, float hi) {
  return (__float_as_uint(lo) >> 16) | (__float_as_uint(hi) & 0xffff0000u);
}

__global__ __launch_bounds__(256) void zero_kernel(int* p, int n) {
  int i = blockIdx.x * 256 + threadIdx.x;
  if (i < n) p[i] = 0;
}

// ---- CSR build ----
__global__ __launch_bounds__(256) void count_edges_kernel(const int* __restrict__ ei, int* __restrict__ deg) {
  int e = blockIdx.x * 256 + threadIdx.x;
  if (e < NE) atomicAdd(&deg[ei[NE + e]], 1);
}
__global__ __launch_bounds__(256) void count_nodes_kernel(const int* __restrict__ cl, int* __restrict__ cdeg) {
  int n = blockIdx.x * 256 + threadIdx.x;
  if (n < NN) atomicAdd(&cdeg[cl[n]], 1);
}

// ---- device-wide exclusive scan, 3 kernels (n % 4 == 0) ----
__global__ __launch_bounds__(256) void scan_partial_kernel(const int* __restrict__ deg, int n,
                                                           int* __restrict__ bsum) {
  int t = threadIdx.x, b = blockIdx.x;
  long base = (long)b * 1024 + t * 4;
  int s = 0;
  if (base < n) {
    int4 v = *reinterpret_cast<const int4*>(deg + base);
    s = (v.x + v.y) + (v.z + v.w);
  }
  __shared__ int l[256];
  l[t] = s;
  __syncthreads();
  for (int off = 128; off > 0; off >>= 1) {
    if (t < off) l[t] += l[t + off];
    __syncthreads();
  }
  if (t == 0) bsum[b] = l[0];
}

__global__ __launch_bounds__(128) void scan_bsums_kernel(int* __restrict__ bsum, int nb) {
  __shared__ int l[128];
  int t = threadIdx.x;
  int v = (t < nb) ? bsum[t] : 0;
  l[t] = v;
  __syncthreads();
  for (int off = 1; off < 128; off <<= 1) {
    int u = (t >= off) ? l[t - off] : 0;
    __syncthreads();
    l[t] += u;
    __syncthreads();
  }
  if (t < nb) bsum[t] = l[t] - v;  // exclusive prefix of block sums
}

__global__ __launch_bounds__(256) void scan_final_kernel(const int* __restrict__ deg, int n,
                                                         const int* __restrict__ bpre,
                                                         int* __restrict__ offs, int* __restrict__ cursor) {
  int t = threadIdx.x, b = blockIdx.x;
  long base = (long)b * 1024 + t * 4;
  int4 v = make_int4(0, 0, 0, 0);
  if (base < n) v = *reinterpret_cast<const int4*>(deg + base);
  int s = (v.x + v.y) + (v.z + v.w);
  __shared__ int l[256];
  l[t] = s;
  __syncthreads();
  for (int off = 1; off < 256; off <<= 1) {
    int u = (t >= off) ? l[t - off] : 0;
    __syncthreads();
    l[t] += u;
    __syncthreads();
  }
  int run = bpre[b] + l[t] - s;  // exclusive global prefix at `base`
  if (base < n) {
    offs[base] = run;     cursor[base] = run;     run += v.x;
    offs[base + 1] = run; cursor[base + 1] = run; run += v.y;
    offs[base + 2] = run; cursor[base + 2] = run; run += v.z;
    offs[base + 3] = run; cursor[base + 3] = run; run += v.w;
    if (base + 4 == n) offs[n] = run;
  }
}

__global__ __launch_bounds__(256) void scatter_edges_kernel(const int* __restrict__ ei, int* __restrict__ cursor,
                                                            int* __restrict__ srclist) {
  int e = blockIdx.x * 256 + threadIdx.x;
  if (e < NE) {
    int t = ei[NE + e];
    int p = atomicAdd(&cursor[t], 1);
    srclist[p] = ei[e];
  }
}
__global__ __launch_bounds__(256) void scatter_nodes_kernel(const int* __restrict__ cl, int* __restrict__ ccursor,
                                                            int* __restrict__ nodelist) {
  int n = blockIdx.x * 256 + threadIdx.x;
  if (n < NN) {
    int p = atomicAdd(&ccursor[cl[n]], 1);
    nodelist[p] = n;
  }
}

// ---- weight prep: fp32 [rows][cols] -> bf16 transposed [cols][rows] ----
struct WtDesc { const float* src; unsigned short* dst; int rows, cols; };
struct WtPack { WtDesc d[6]; };
__global__ __launch_bounds__(256) void wprep_kernel(WtPack p) {
  long stride = (long)gridDim.x * 256;
  for (int a = 0; a < 6; ++a) {
    int rows = p.d[a].rows, cols = p.d[a].cols, n = rows * cols;
    const float* src = p.d[a].src;
    unsigned short* dst = p.d[a].dst;
    for (long i = (long)blockIdx.x * 256 + threadIdx.x; i < n; i += stride) {
      int r = (int)(i / cols), c = (int)(i % cols);
      dst[(long)c * rows + r] = f2bf(src[(long)r * cols + c]);
    }
  }
}

// ---- MFMA MLP: Linear(C->64) + LN + ReLU + Linear(64->C) ----
// Block = 64 nodes (4 waves x 16). A-layout: A[m=lane&15][k=quad*8+j];
// C/D layout: col=lane&15, row=quad*4+reg.
template<int C, bool INF32>
__global__ __launch_bounds__(256) void mlp_mfma_kernel(
    const void* __restrict__ xin_v,
    const unsigned short* __restrict__ W1T,  // bf16 [64][C]
    const float* __restrict__ b1, const float* __restrict__ g, const float* __restrict__ be,
    const unsigned short* __restrict__ W2T,  // bf16 [C][64]
    const float* __restrict__ b2,
    unsigned short* __restrict__ out, int outstride)
{
  constexpr int CP = C + 8;
  __shared__ unsigned short xs[64 * CP];
  __shared__ unsigned short ps[64 * 72];
  int tid = threadIdx.x;
  long nb = (long)blockIdx.x * 64;

  if constexpr (INF32) {
    const float* xf = (const float*)xin_v;
    constexpr int TOT = 64 * (C / 4);
    for (int i = tid; i < TOT; i += 256) {
      int r = i / (C / 4), cc = i % (C / 4);
      long row = nb + r; if (row >= NN) row = NN - 1;
      float4 v = reinterpret_cast<const float4*>(xf + row * C)[cc];
      unsigned int* dst = (unsigned int*)&xs[r * CP + cc * 4];
      dst[0] = (unsigned int)f2bf(v.x) | ((unsigned int)f2bf(v.y) << 16);
      dst[1] = (unsigned int)f2bf(v.z) | ((unsigned int)f2bf(v.w) << 16);
    }
  } else {
    const unsigned short* xh = (const unsigned short*)xin_v;
    constexpr int TOT = 64 * (C / 8);
    for (int i = tid; i < TOT; i += 256) {
      int r = i / (C / 8), cc = i % (C / 8);
      long row = nb + r; if (row >= NN) row = NN - 1;
      uint4 u = reinterpret_cast<const uint4*>(xh + row * C)[cc];
      *reinterpret_cast<uint4*>(&xs[r * CP + cc * 8]) = u;
    }
  }
  __syncthreads();

  int wv = tid >> 6, lane = tid & 63;
  int l15 = lane & 15, q = lane >> 4;
  int mrow = wv * 16;

  float b1v[4], gv[4], bev[4];
  #pragma unroll
  for (int t = 0; t < 4; ++t) {
    b1v[t] = b1[t * 16 + l15];
    gv[t]  = g[t * 16 + l15];
    bev[t] = be[t * 16 + l15];
  }

  f32x4 acc[4];
  #pragma unroll
  for (int t = 0; t < 4; ++t) acc[t] = (f32x4){0.f, 0.f, 0.f, 0.f};
  #pragma unroll
  for (int kk = 0; kk < C / 32; ++kk) {
    short8 a = *reinterpret_cast<const short8*>(&xs[(mrow + l15) * CP + kk * 32 + q * 8]);
    #pragma unroll
    for (int t = 0; t < 4; ++t) {
      short8 b = *reinterpret_cast<const short8*>(&W1T[(t * 16 + l15) * C + kk * 32 + q * 8]);
      acc[t] = __builtin_amdgcn_mfma_f32_16x16x32_bf16(a, b, acc[t], 0, 0, 0);
    }
  }

  float vout[4][4];
  #pragma unroll
  for (int r = 0; r < 4; ++r) {
    float h0 = acc[0][r] + b1v[0];
    float h1 = acc[1][r] + b1v[1];
    float h2 = acc[2][r] + b1v[2];
    float h3 = acc[3][r] + b1v[3];
    float s = (h0 + h1) + (h2 + h3);
    s += __shfl_xor(s, 1); s += __shfl_xor(s, 2);
    s += __shfl_xor(s, 4); s += __shfl_xor(s, 8);
    float mu = s * (1.0f / 64.0f);
    float d0 = h0 - mu, d1 = h1 - mu, d2 = h2 - mu, d3 = h3 - mu;
    float qs = (d0 * d0 + d1 * d1) + (d2 * d2 + d3 * d3);
    qs += __shfl_xor(qs, 1); qs += __shfl_xor(qs, 2);
    qs += __shfl_xor(qs, 4); qs += __shfl_xor(qs, 8);
    float rinv = rsqrtf(qs * (1.0f / 64.0f) + 1e-5f);
    vout[0][r] = fmaxf(0.f, d0 * rinv * gv[0] + bev[0]);
    vout[1][r] = fmaxf(0.f, d1 * rinv * gv[1] + bev[1]);
    vout[2][r] = fmaxf(0.f, d2 * rinv * gv[2] + bev[2]);
    vout[3][r] = fmaxf(0.f, d3 * rinv * gv[3] + bev[3]);
  }

  #pragma unroll
  for (int t = 0; t < 4; ++t)
    #pragma unroll
    for (int r = 0; r < 4; ++r)
      ps[(mrow + q * 4 + r) * 72 + t * 16 + l15] = f2bf(vout[t][r]);

  constexpr int NT2 = C / 16;
  f32x4 acc2[NT2];
  #pragma unroll
  for (int tc = 0; tc < NT2; ++tc) acc2[tc] = (f32x4){0.f, 0.f, 0.f, 0.f};
  #pragma unroll
  for (int s = 0; s < 2; ++s) {
    short8 a = *reinterpret_cast<const short8*>(&ps[(mrow + l15) * 72 + s * 32 + q * 8]);
    #pragma unroll
    for (int tc = 0; tc < NT2; ++tc) {
      short8 b = *reinterpret_cast<const short8*>(&W2T[(tc * 16 + l15) * 64 + s * 32 + q * 8]);
      acc2[tc] = __builtin_amdgcn_mfma_f32_16x16x32_bf16(a, b, acc2[tc], 0, 0, 0);
    }
  }

  #pragma unroll
  for (int tc = 0; tc < NT2; ++tc) {
    float bb = b2[tc * 16 + l15];
    #pragma unroll
    for (int r = 0; r < 4; ++r) {
      long node = nb + mrow + q * 4 + r;
      if (node < NN) out[node * (long)outstride + tc * 16 + l15] = f2bf(acc2[tc][r] + bb);
    }
  }
}

// ---- per-target max aggregation over CSR in-edges (bf16 storage) ----
template<int C>
__global__ __launch_bounds__(256) void aggr_kernel(
    const int* __restrict__ offs, const int* __restrict__ srclist,
    unsigned short* __restrict__ xnext)
{
  constexpr int Q = C / 8;
  constexpr int NPB = 256 / Q;
  int q = threadIdx.x & (Q - 1);
  int ln = threadIdx.x / Q;
  long node = (long)blockIdx.x * NPB + ln;
  int beg = offs[node], end = offs[node + 1];
  float m[8];
  #pragma unroll
  for (int k = 0; k < 8; ++k) m[k] = -3.4e38f;
  for (int e = beg; e < end; ++e) {
    int sidx = srclist[e];
    uint4 u = reinterpret_cast<const uint4*>(xnext + (long)sidx * (2 * C))[q];
    m[0] = fmaxf(m[0], bflo(u.x)); m[1] = fmaxf(m[1], bfhi(u.x));
    m[2] = fmaxf(m[2], bflo(u.y)); m[3] = fmaxf(m[3], bfhi(u.y));
    m[4] = fmaxf(m[4], bflo(u.z)); m[5] = fmaxf(m[5], bfhi(u.z));
    m[6] = fmaxf(m[6], bflo(u.w)); m[7] = fmaxf(m[7], bfhi(u.w));
  }
  if (beg == end) {
    #pragma unroll
    for (int k = 0; k < 8; ++k) m[k] = 0.f;
  }
  uint4 o;
  o.x = packbf_exact(m[0], m[1]);
  o.y = packbf_exact(m[2], m[3]);
  o.z = packbf_exact(m[4], m[5]);
  o.w = packbf_exact(m[6], m[7]);
  reinterpret_cast<uint4*>(xnext + (long)node * (2 * C) + C)[q] = o;
}

// ---- cluster max-pool: x3 bf16 [N,512] -> pooled fp32 [NC,512] ----
__global__ __launch_bounds__(256) void pool_kernel(
    const int* __restrict__ coffs, const int* __restrict__ nodelist,
    const unsigned short* __restrict__ x3, float* __restrict__ pooled)
{
  int q = threadIdx.x & 63;
  int lc = threadIdx.x >> 6;
  long k = (long)blockIdx.x * 4 + lc;
  int beg = coffs[k], end = coffs[k + 1];
  float m[8];
  #pragma unroll
  for (int t = 0; t < 8; ++t) m[t] = -3.4e38f;
  for (int e = beg; e < end; ++e) {
    int n = nodelist[e];
    uint4 u = reinterpret_cast<const uint4*>(x3 + (long)n * 512)[q];
    m[0] = fmaxf(m[0], bflo(u.x)); m[1] = fmaxf(m[1], bfhi(u.x));
    m[2] = fmaxf(m[2], bflo(u.y)); m[3] = fmaxf(m[3], bfhi(u.y));
    m[4] = fmaxf(m[4], bflo(u.z)); m[5] = fmaxf(m[5], bfhi(u.z));
    m[6] = fmaxf(m[6], bflo(u.w)); m[7] = fmaxf(m[7], bfhi(u.w));
  }
  if (beg == end) {
    #pragma unroll
    for (int t = 0; t < 8; ++t) m[t] = 0.f;
  }
  float* orow = pooled + k * 512 + q * 8;
  reinterpret_cast<float4*>(orow)[0] = make_float4(m[0], m[1], m[2], m[3]);
  reinterpret_cast<float4*>(orow)[1] = make_float4(m[4], m[5], m[6], m[7]);
}

__global__ __launch_bounds__(256) void colnorm_kernel(const float* __restrict__ pooled,
                                                      float* __restrict__ normsq) {
  int tid = threadIdx.x;
  int rows_per = (NCL + gridDim.x - 1) / gridDim.x;
  int r0 = blockIdx.x * rows_per;
  int r1 = min(r0 + rows_per, NCL);
  float s0 = 0.f, s1 = 0.f;
  for (int r = r0; r < r1; ++r) {
    float a = pooled[(long)r * 512 + tid];
    float b = pooled[(long)r * 512 + 256 + tid];
    s0 = fmaf(a, a, s0);
    s1 = fmaf(b, b, s1);
  }
  atomicAdd(&normsq[tid], s0);
  atomicAdd(&normsq[tid + 256], s1);
}

__global__ __launch_bounds__(256) void normalize_kernel(const float* __restrict__ pooled,
                                                        const float* __restrict__ normsq,
                                                        float* __restrict__ out) {
  long idx = (long)blockIdx.x * 256 + threadIdx.x;
  if (idx < (long)NCL * 512) {
    float nv = normsq[idx & 511];
    out[idx] = pooled[idx] * rsqrtf(nv);
  }
}

extern "C" void kernel_launch(void* const* d_in, const int* in_sizes, int n_in,
                              void* d_out, int out_size, void* d_ws, size_t ws_size,
                              hipStream_t stream) {
  const float* x0 = (const float*)d_in[0];
  const int* ei = (const int*)d_in[1];
  const int* cl = (const int*)d_in[2];

  const float* W1f[3]; const float* b1f[3]; const float* gf[3];
  const float* bef[3]; const float* W2f[3]; const float* b2f[3];
  for (int i = 0; i < 3; ++i) {
    W1f[i] = (const float*)d_in[3 + 6 * i + 0];
    b1f[i] = (const float*)d_in[3 + 6 * i + 1];
    gf[i]  = (const float*)d_in[3 + 6 * i + 2];
    bef[i] = (const float*)d_in[3 + 6 * i + 3];
    W2f[i] = (const float*)d_in[3 + 6 * i + 4];
    b2f[i] = (const float*)d_in[3 + 6 * i + 5];
  }

  char* ws = (char*)d_ws;
  size_t off = 0;
  auto take = [&](size_t bytes) {
    size_t o = off; off = (off + bytes + 255) & ~(size_t)255; return o;
  };
  unsigned short* x3 = (unsigned short*)(ws + take((size_t)NN * 512 * 2));
  unsigned short* x1 = x3;  // x1 dead before x3 written
  unsigned short* x2 = (unsigned short*)(ws + take((size_t)NN * 256 * 2));
  float* pooled = (float*)(ws + take((size_t)NCL * 512 * 4));
  int* zero_base = (int*)(ws + take((size_t)(NN + NCL + 512) * 4));
  int* deg = zero_base;
  int* cdeg = zero_base + NN;
  float* normsq = (float*)(zero_base + NN + NCL);
  int* offs = (int*)(ws + take((size_t)(NN + 1) * 4));
  int* cursor = (int*)(ws + take((size_t)NN * 4));
  int* srclist = (int*)(ws + take((size_t)NE * 4));
  int* coffs = (int*)(ws + take((size_t)(NCL + 1) * 4));
  int* ccursor = (int*)(ws + take((size_t)NCL * 4));
  int* nodelist = (int*)(ws + take((size_t)NN * 4));
  int* bsumN = (int*)(ws + take(128 * 4));
  int* bsumC = (int*)(ws + take(128 * 4));

  int Cs[3] = {64, 128, 256};
  unsigned short *W1T[3], *W2T[3];
  for (int i = 0; i < 3; ++i) {
    W1T[i] = (unsigned short*)(ws + take((size_t)64 * Cs[i] * 2));
    W2T[i] = (unsigned short*)(ws + take((size_t)Cs[i] * 64 * 2));
  }

  if (off > ws_size) return;  // clean-fail guard

  int zn = NN + NCL + 512;
  zero_kernel<<<(zn + 255) / 256, 256, 0, stream>>>(zero_base, zn);
  count_edges_kernel<<<(NE + 255) / 256, 256, 0, stream>>>(ei, deg);
  count_nodes_kernel<<<(NN + 255) / 256, 256, 0, stream>>>(cl, cdeg);

  int nbN = (NN + 1023) / 1024;   // 98
  int nbC = (NCL + 1023) / 1024;  // 10
  scan_partial_kernel<<<nbN, 256, 0, stream>>>(deg, NN, bsumN);
  scan_bsums_kernel<<<1, 128, 0, stream>>>(bsumN, nbN);
  scan_final_kernel<<<nbN, 256, 0, stream>>>(deg, NN, bsumN, offs, cursor);
  scan_partial_kernel<<<nbC, 256, 0, stream>>>(cdeg, NCL, bsumC);
  scan_bsums_kernel<<<1, 128, 0, stream>>>(bsumC, nbC);
  scan_final_kernel<<<nbC, 256, 0, stream>>>(cdeg, NCL, bsumC, coffs, ccursor);

  scatter_edges_kernel<<<(NE + 255) / 256, 256, 0, stream>>>(ei, cursor, srclist);
  scatter_nodes_kernel<<<(NN + 255) / 256, 256, 0, stream>>>(cl, ccursor, nodelist);

  WtPack wp;
  for (int i = 0; i < 3; ++i) {
    wp.d[2 * i + 0] = { W1f[i], W1T[i], Cs[i], 64 };
    wp.d[2 * i + 1] = { W2f[i], W2T[i], 64, Cs[i] };
  }
  wprep_kernel<<<32, 256, 0, stream>>>(wp);

  int nblk = (NN + 63) / 64;  // 1563
  mlp_mfma_kernel<64, true><<<nblk, 256, 0, stream>>>(
      x0, W1T[0], b1f[0], gf[0], bef[0], W2T[0], b2f[0], x1, 128);
  aggr_kernel<64><<<NN / 32, 256, 0, stream>>>(offs, srclist, x1);
  mlp_mfma_kernel<128, false><<<nblk, 256, 0, stream>>>(
      x1, W1T[1], b1f[1], gf[1], bef[1], W2T[1], b2f[1], x2, 256);
  aggr_kernel<128><<<NN / 16, 256, 0, stream>>>(offs, srclist, x2);
  mlp_mfma_kernel<256, false><<<nblk, 256, 0, stream>>>(
      x2, W1T[2], b1f[2], gf[2], bef[2], W2T[2], b2f[2], x3, 512);
  aggr_kernel<256><<<NN / 8, 256, 0, stream>>>(offs, srclist, x3);

  pool_kernel<<<NCL / 4, 256, 0, stream>>>(coffs, nodelist, x3, pooled);
  colnorm_kernel<<<128, 256, 0, stream>>>(pooled, normsq);
  normalize_kernel<<<((long)NCL * 512 + 255) / 256, 256, 0, stream>>>(pooled, normsq, (float*)d_out);
}

// Round 6
// 546.425 us; speedup vs baseline: 2.3489x; 1.0337x over previous
//
#include <hip/hip_runtime.h>
#include <hip/hip_bf16.h>

#define NN 100000
#define NE 800000
#define NCL 10000

typedef __attribute__((ext_vector_type(8))) short short8;
typedef __attribute__((ext_vector_type(4))) float f32x4;

__device__ __forceinline__ float bflo(unsigned int u) {
  return __uint_as_float(u << 16);
}
__device__ __forceinline__ float bfhi(unsigned int u) {
  return __uint_as_float(u & 0xffff0000u);
}
__device__ __forceinline__ unsigned short f2bf(float f) {
  unsigned int u = __float_as_uint(f);
  u += 0x7fffu + ((u >> 16) & 1u);
  return (unsigned short)(u >> 16);
}
__device__ __forceinline__ unsigned int packbf_exact(float lo, float hi) {
  return (__float_as_uint(lo) >> 16) | (__float_as_uint(hi) & 0xffff0000u);
}

__global__ __launch_bounds__(256) void zero_kernel(int* p, int n) {
  int i = blockIdx.x * 256 + threadIdx.x;
  if (i < n) p[i] = 0;
}

// ---- CSR build: merged counts (edges by target + nodes by cluster) ----
__global__ __launch_bounds__(256) void count_both_kernel(const int* __restrict__ ei, int* __restrict__ deg,
                                                         const int* __restrict__ cl, int* __restrict__ cdeg) {
  int i = blockIdx.x * 256 + threadIdx.x;
  if (i < NE) {
    atomicAdd(&deg[ei[NE + i]], 1);
  } else if (i < NE + NN) {
    atomicAdd(&cdeg[cl[i - NE]], 1);
  }
}

// ---- device-wide exclusive scan for both arrays (merged 3-phase) ----
__global__ __launch_bounds__(256) void scan_partial_both_kernel(
    const int* __restrict__ degN, int* __restrict__ bsumN, int nbN,
    const int* __restrict__ degC, int* __restrict__ bsumC) {
  int t = threadIdx.x, b = blockIdx.x;
  const int* deg; int* bsum; int n; int bb;
  if (b < nbN) { deg = degN; bsum = bsumN; n = NN; bb = b; }
  else         { deg = degC; bsum = bsumC; n = NCL; bb = b - nbN; }
  long base = (long)bb * 1024 + t * 4;
  int s = 0;
  if (base < n) {
    int4 v = *reinterpret_cast<const int4*>(deg + base);
    s = (v.x + v.y) + (v.z + v.w);
  }
  __shared__ int l[256];
  l[t] = s;
  __syncthreads();
  for (int off = 128; off > 0; off >>= 1) {
    if (t < off) l[t] += l[t + off];
    __syncthreads();
  }
  if (t == 0) bsum[bb] = l[0];
}

__global__ __launch_bounds__(128) void scan_bsums_both_kernel(int* __restrict__ bsumN, int nbN,
                                                              int* __restrict__ bsumC, int nbC) {
  int* bsum = (blockIdx.x == 0) ? bsumN : bsumC;
  int nb = (blockIdx.x == 0) ? nbN : nbC;
  __shared__ int l[128];
  int t = threadIdx.x;
  int v = (t < nb) ? bsum[t] : 0;
  l[t] = v;
  __syncthreads();
  for (int off = 1; off < 128; off <<= 1) {
    int u = (t >= off) ? l[t - off] : 0;
    __syncthreads();
    l[t] += u;
    __syncthreads();
  }
  if (t < nb) bsum[t] = l[t] - v;  // exclusive prefix of block sums
}

__global__ __launch_bounds__(256) void scan_final_both_kernel(
    const int* __restrict__ degN, const int* __restrict__ bpreN,
    int* __restrict__ offsN, int* __restrict__ curN, int nbN,
    const int* __restrict__ degC, const int* __restrict__ bpreC,
    int* __restrict__ offsC, int* __restrict__ curC) {
  int t = threadIdx.x, b = blockIdx.x;
  const int* deg; const int* bpre; int* offs; int* cursor; int n; int bb;
  if (b < nbN) { deg = degN; bpre = bpreN; offs = offsN; cursor = curN; n = NN; bb = b; }
  else         { deg = degC; bpre = bpreC; offs = offsC; cursor = curC; n = NCL; bb = b - nbN; }
  long base = (long)bb * 1024 + t * 4;
  int4 v = make_int4(0, 0, 0, 0);
  if (base < n) v = *reinterpret_cast<const int4*>(deg + base);
  int s = (v.x + v.y) + (v.z + v.w);
  __shared__ int l[256];
  l[t] = s;
  __syncthreads();
  for (int off = 1; off < 256; off <<= 1) {
    int u = (t >= off) ? l[t - off] : 0;
    __syncthreads();
    l[t] += u;
    __syncthreads();
  }
  int run = bpre[bb] + l[t] - s;
  if (base < n) {
    offs[base] = run;     cursor[base] = run;     run += v.x;
    offs[base + 1] = run; cursor[base + 1] = run; run += v.y;
    offs[base + 2] = run; cursor[base + 2] = run; run += v.z;
    offs[base + 3] = run; cursor[base + 3] = run; run += v.w;
    if (base + 4 == n) offs[n] = run;
  }
}

__global__ __launch_bounds__(256) void scatter_both_kernel(
    const int* __restrict__ ei, int* __restrict__ cursor, int* __restrict__ srclist,
    const int* __restrict__ cl, int* __restrict__ ccursor, int* __restrict__ nodelist) {
  int i = blockIdx.x * 256 + threadIdx.x;
  if (i < NE) {
    int t = ei[NE + i];
    int p = atomicAdd(&cursor[t], 1);
    srclist[p] = ei[i];
  } else if (i < NE + NN) {
    int n = i - NE;
    int p = atomicAdd(&ccursor[cl[n]], 1);
    nodelist[p] = n;
  }
}

// ---- weight prep: fp32 [rows][cols] -> bf16 transposed [cols][rows] ----
struct WtDesc { const float* src; unsigned short* dst; int rows, cols; };
struct WtPack { WtDesc d[6]; };
__global__ __launch_bounds__(256) void wprep_kernel(WtPack p) {
  long stride = (long)gridDim.x * 256;
  for (int a = 0; a < 6; ++a) {
    int rows = p.d[a].rows, cols = p.d[a].cols, n = rows * cols;
    const float* src = p.d[a].src;
    unsigned short* dst = p.d[a].dst;
    for (long i = (long)blockIdx.x * 256 + threadIdx.x; i < n; i += stride) {
      int r = (int)(i / cols), c = (int)(i % cols);
      dst[(long)c * rows + r] = f2bf(src[(long)r * cols + c]);
    }
  }
}

// ---- MFMA MLP: Linear(C->64) + LN + ReLU + Linear(64->C) ----
// Block = 64 nodes (4 waves x 16). No X staging: A-fragments
// (A[m=lane&15][k=quad*8+j]) are 16B-contiguous per lane -> direct global
// loads. GEMM2 output streamed per 16-col tile to keep VGPRs low. Only LDS
// use is the 9KB P-matrix layout round-trip (wave-private rows, no barrier).
template<int C, bool INF32>
__global__ __launch_bounds__(256) void mlp_mfma_kernel(
    const void* __restrict__ xin_v,
    const unsigned short* __restrict__ W1T,  // bf16 [64][C]
    const float* __restrict__ b1, const float* __restrict__ g, const float* __restrict__ be,
    const unsigned short* __restrict__ W2T,  // bf16 [C][64]
    const float* __restrict__ b2,
    unsigned short* __restrict__ out, int outstride)
{
  __shared__ unsigned short ps[64 * 72];
  int tid = threadIdx.x;
  long nb = (long)blockIdx.x * 64;
  int wv = tid >> 6, lane = tid & 63;
  int l15 = lane & 15, q = lane >> 4;
  int mrow = wv * 16;
  long arow = nb + mrow + l15;
  if (arow >= NN) arow = NN - 1;  // clamp (stores are guarded)

  float b1v[4], gv[4], bev[4];
  #pragma unroll
  for (int t = 0; t < 4; ++t) {
    b1v[t] = b1[t * 16 + l15];
    gv[t]  = g[t * 16 + l15];
    bev[t] = be[t * 16 + l15];
  }

  // GEMM1: H1[m][n] = X[m][:] . W1[:][n]; A direct from global
  f32x4 acc[4];
  #pragma unroll
  for (int t = 0; t < 4; ++t) acc[t] = (f32x4){0.f, 0.f, 0.f, 0.f};
  #pragma unroll
  for (int kk = 0; kk < C / 32; ++kk) {
    short8 a;
    if constexpr (INF32) {
      const float* xf = (const float*)xin_v;
      const float* src = xf + arow * C + kk * 32 + q * 8;
      float4 v0 = reinterpret_cast<const float4*>(src)[0];
      float4 v1 = reinterpret_cast<const float4*>(src)[1];
      a[0] = (short)f2bf(v0.x); a[1] = (short)f2bf(v0.y);
      a[2] = (short)f2bf(v0.z); a[3] = (short)f2bf(v0.w);
      a[4] = (short)f2bf(v1.x); a[5] = (short)f2bf(v1.y);
      a[6] = (short)f2bf(v1.z); a[7] = (short)f2bf(v1.w);
    } else {
      const unsigned short* xh = (const unsigned short*)xin_v;
      a = *reinterpret_cast<const short8*>(xh + arow * C + kk * 32 + q * 8);
    }
    #pragma unroll
    for (int t = 0; t < 4; ++t) {
      short8 b = *reinterpret_cast<const short8*>(&W1T[(t * 16 + l15) * C + kk * 32 + q * 8]);
      acc[t] = __builtin_amdgcn_mfma_f32_16x16x32_bf16(a, b, acc[t], 0, 0, 0);
    }
  }

  // epilogue1: +b1, LayerNorm over the 64 hidden channels, ReLU
  float vout[4][4];
  #pragma unroll
  for (int r = 0; r < 4; ++r) {
    float h0 = acc[0][r] + b1v[0];
    float h1 = acc[1][r] + b1v[1];
    float h2 = acc[2][r] + b1v[2];
    float h3 = acc[3][r] + b1v[3];
    float s = (h0 + h1) + (h2 + h3);
    s += __shfl_xor(s, 1); s += __shfl_xor(s, 2);
    s += __shfl_xor(s, 4); s += __shfl_xor(s, 8);
    float mu = s * (1.0f / 64.0f);
    float d0 = h0 - mu, d1 = h1 - mu, d2 = h2 - mu, d3 = h3 - mu;
    float qs = (d0 * d0 + d1 * d1) + (d2 * d2 + d3 * d3);
    qs += __shfl_xor(qs, 1); qs += __shfl_xor(qs, 2);
    qs += __shfl_xor(qs, 4); qs += __shfl_xor(qs, 8);
    float rinv = rsqrtf(qs * (1.0f / 64.0f) + 1e-5f);
    vout[0][r] = fmaxf(0.f, d0 * rinv * gv[0] + bev[0]);
    vout[1][r] = fmaxf(0.f, d1 * rinv * gv[1] + bev[1]);
    vout[2][r] = fmaxf(0.f, d2 * rinv * gv[2] + bev[2]);
    vout[3][r] = fmaxf(0.f, d3 * rinv * gv[3] + bev[3]);
  }

  // P -> LDS (C/D layout -> row-major); rows wave-private, no barrier
  #pragma unroll
  for (int t = 0; t < 4; ++t)
    #pragma unroll
    for (int r = 0; r < 4; ++r)
      ps[(mrow + q * 4 + r) * 72 + t * 16 + l15] = f2bf(vout[t][r]);

  // GEMM2: A-frags for both K-halves, then stream the output tiles
  short8 a0 = *reinterpret_cast<const short8*>(&ps[(mrow + l15) * 72 + q * 8]);
  short8 a1 = *reinterpret_cast<const short8*>(&ps[(mrow + l15) * 72 + 32 + q * 8]);
  long node0 = nb + mrow + q * 4;
  constexpr int NT2 = C / 16;
  #pragma unroll
  for (int tc = 0; tc < NT2; ++tc) {
    short8 b0 = *reinterpret_cast<const short8*>(&W2T[(tc * 16 + l15) * 64 + q * 8]);
    short8 b1w = *reinterpret_cast<const short8*>(&W2T[(tc * 16 + l15) * 64 + 32 + q * 8]);
    f32x4 c = (f32x4){0.f, 0.f, 0.f, 0.f};
    c = __builtin_amdgcn_mfma_f32_16x16x32_bf16(a0, b0, c, 0, 0, 0);
    c = __builtin_amdgcn_mfma_f32_16x16x32_bf16(a1, b1w, c, 0, 0, 0);
    float bb = b2[tc * 16 + l15];
    #pragma unroll
    for (int r = 0; r < 4; ++r) {
      long node = node0 + r;
      if (node < NN) out[node * (long)outstride + tc * 16 + l15] = f2bf(c[r] + bb);
    }
  }
}

// ---- per-target max aggregation over CSR in-edges (bf16 storage) ----
template<int C>
__global__ __launch_bounds__(256) void aggr_kernel(
    const int* __restrict__ offs, const int* __restrict__ srclist,
    unsigned short* __restrict__ xnext)
{
  constexpr int Q = C / 8;
  constexpr int NPB = 256 / Q;
  int q = threadIdx.x & (Q - 1);
  int ln = threadIdx.x / Q;
  long node = (long)blockIdx.x * NPB + ln;
  int beg = offs[node], end = offs[node + 1];
  float m[8];
  #pragma unroll
  for (int k = 0; k < 8; ++k) m[k] = -3.4e38f;
  for (int e = beg; e < end; ++e) {
    int sidx = srclist[e];
    uint4 u = reinterpret_cast<const uint4*>(xnext + (long)sidx * (2 * C))[q];
    m[0] = fmaxf(m[0], bflo(u.x)); m[1] = fmaxf(m[1], bfhi(u.x));
    m[2] = fmaxf(m[2], bflo(u.y)); m[3] = fmaxf(m[3], bfhi(u.y));
    m[4] = fmaxf(m[4], bflo(u.z)); m[5] = fmaxf(m[5], bfhi(u.z));
    m[6] = fmaxf(m[6], bflo(u.w)); m[7] = fmaxf(m[7], bfhi(u.w));
  }
  if (beg == end) {
    #pragma unroll
    for (int k = 0; k < 8; ++k) m[k] = 0.f;
  }
  uint4 o;
  o.x = packbf_exact(m[0], m[1]);
  o.y = packbf_exact(m[2], m[3]);
  o.z = packbf_exact(m[4], m[5]);
  o.w = packbf_exact(m[6], m[7]);
  reinterpret_cast<uint4*>(xnext + (long)node * (2 * C) + C)[q] = o;
}

// ---- cluster max-pool: x3 bf16 [N,512] -> pooled fp32 [NC,512] ----
__global__ __launch_bounds__(256) void pool_kernel(
    const int* __restrict__ coffs, const int* __restrict__ nodelist,
    const unsigned short* __restrict__ x3, float* __restrict__ pooled)
{
  int q = threadIdx.x & 63;
  int lc = threadIdx.x >> 6;
  long k = (long)blockIdx.x * 4 + lc;
  int beg = coffs[k], end = coffs[k + 1];
  float m[8];
  #pragma unroll
  for (int t = 0; t < 8; ++t) m[t] = -3.4e38f;
  for (int e = beg; e < end; ++e) {
    int n = nodelist[e];
    uint4 u = reinterpret_cast<const uint4*>(x3 + (long)n * 512)[q];
    m[0] = fmaxf(m[0], bflo(u.x)); m[1] = fmaxf(m[1], bfhi(u.x));
    m[2] = fmaxf(m[2], bflo(u.y)); m[3] = fmaxf(m[3], bfhi(u.y));
    m[4] = fmaxf(m[4], bflo(u.z)); m[5] = fmaxf(m[5], bfhi(u.z));
    m[6] = fmaxf(m[6], bflo(u.w)); m[7] = fmaxf(m[7], bfhi(u.w));
  }
  if (beg == end) {
    #pragma unroll
    for (int t = 0; t < 8; ++t) m[t] = 0.f;
  }
  float* orow = pooled + k * 512 + q * 8;
  reinterpret_cast<float4*>(orow)[0] = make_float4(m[0], m[1], m[2], m[3]);
  reinterpret_cast<float4*>(orow)[1] = make_float4(m[4], m[5], m[6], m[7]);
}

__global__ __launch_bounds__(256) void colnorm_kernel(const float* __restrict__ pooled,
                                                      float* __restrict__ normsq) {
  int tid = threadIdx.x;
  int rows_per = (NCL + gridDim.x - 1) / gridDim.x;
  int r0 = blockIdx.x * rows_per;
  int r1 = min(r0 + rows_per, NCL);
  float s0 = 0.f, s1 = 0.f;
  for (int r = r0; r < r1; ++r) {
    float a = pooled[(long)r * 512 + tid];
    float b = pooled[(long)r * 512 + 256 + tid];
    s0 = fmaf(a, a, s0);
    s1 = fmaf(b, b, s1);
  }
  atomicAdd(&normsq[tid], s0);
  atomicAdd(&normsq[tid + 256], s1);
}

__global__ __launch_bounds__(256) void normalize_kernel(const float* __restrict__ pooled,
                                                        const float* __restrict__ normsq,
                                                        float* __restrict__ out) {
  long idx = (long)blockIdx.x * 256 + threadIdx.x;
  if (idx < (long)NCL * 512) {
    float nv = normsq[idx & 511];
    out[idx] = pooled[idx] * rsqrtf(nv);
  }
}

extern "C" void kernel_launch(void* const* d_in, const int* in_sizes, int n_in,
                              void* d_out, int out_size, void* d_ws, size_t ws_size,
                              hipStream_t stream) {
  const float* x0 = (const float*)d_in[0];
  const int* ei = (const int*)d_in[1];
  const int* cl = (const int*)d_in[2];

  const float* W1f[3]; const float* b1f[3]; const float* gf[3];
  const float* bef[3]; const float* W2f[3]; const float* b2f[3];
  for (int i = 0; i < 3; ++i) {
    W1f[i] = (const float*)d_in[3 + 6 * i + 0];
    b1f[i] = (const float*)d_in[3 + 6 * i + 1];
    gf[i]  = (const float*)d_in[3 + 6 * i + 2];
    bef[i] = (const float*)d_in[3 + 6 * i + 3];
    W2f[i] = (const float*)d_in[3 + 6 * i + 4];
    b2f[i] = (const float*)d_in[3 + 6 * i + 5];
  }

  char* ws = (char*)d_ws;
  size_t off = 0;
  auto take = [&](size_t bytes) {
    size_t o = off; off = (off + bytes + 255) & ~(size_t)255; return o;
  };
  unsigned short* x3 = (unsigned short*)(ws + take((size_t)NN * 512 * 2));
  unsigned short* x1 = x3;  // x1 dead before x3 written
  unsigned short* x2 = (unsigned short*)(ws + take((size_t)NN * 256 * 2));
  float* pooled = (float*)(ws + take((size_t)NCL * 512 * 4));
  int* zero_base = (int*)(ws + take((size_t)(NN + NCL + 512) * 4));
  int* deg = zero_base;
  int* cdeg = zero_base + NN;
  float* normsq = (float*)(zero_base + NN + NCL);
  int* offs = (int*)(ws + take((size_t)(NN + 1) * 4));
  int* cursor = (int*)(ws + take((size_t)NN * 4));
  int* srclist = (int*)(ws + take((size_t)NE * 4));
  int* coffs = (int*)(ws + take((size_t)(NCL + 1) * 4));
  int* ccursor = (int*)(ws + take((size_t)NCL * 4));
  int* nodelist = (int*)(ws + take((size_t)NN * 4));
  int* bsumN = (int*)(ws + take(128 * 4));
  int* bsumC = (int*)(ws + take(128 * 4));

  int Cs[3] = {64, 128, 256};
  unsigned short *W1T[3], *W2T[3];
  for (int i = 0; i < 3; ++i) {
    W1T[i] = (unsigned short*)(ws + take((size_t)64 * Cs[i] * 2));
    W2T[i] = (unsigned short*)(ws + take((size_t)Cs[i] * 64 * 2));
  }

  if (off > ws_size) return;  // clean-fail guard

  int zn = NN + NCL + 512;
  zero_kernel<<<(zn + 255) / 256, 256, 0, stream>>>(zero_base, zn);
  count_both_kernel<<<(NE + NN + 255) / 256, 256, 0, stream>>>(ei, deg, cl, cdeg);

  int nbN = (NN + 1023) / 1024;   // 98
  int nbC = (NCL + 1023) / 1024;  // 10
  scan_partial_both_kernel<<<nbN + nbC, 256, 0, stream>>>(deg, bsumN, nbN, cdeg, bsumC);
  scan_bsums_both_kernel<<<2, 128, 0, stream>>>(bsumN, nbN, bsumC, nbC);
  scan_final_both_kernel<<<nbN + nbC, 256, 0, stream>>>(deg, bsumN, offs, cursor, nbN,
                                                        cdeg, bsumC, coffs, ccursor);
  scatter_both_kernel<<<(NE + NN + 255) / 256, 256, 0, stream>>>(ei, cursor, srclist,
                                                                 cl, ccursor, nodelist);

  WtPack wp;
  for (int i = 0; i < 3; ++i) {
    wp.d[2 * i + 0] = { W1f[i], W1T[i], Cs[i], 64 };
    wp.d[2 * i + 1] = { W2f[i], W2T[i], 64, Cs[i] };
  }
  wprep_kernel<<<32, 256, 0, stream>>>(wp);

  int nblk = (NN + 63) / 64;  // 1563
  mlp_mfma_kernel<64, true><<<nblk, 256, 0, stream>>>(
      x0, W1T[0], b1f[0], gf[0], bef[0], W2T[0], b2f[0], x1, 128);
  aggr_kernel<64><<<NN / 32, 256, 0, stream>>>(offs, srclist, x1);
  mlp_mfma_kernel<128, false><<<nblk, 256, 0, stream>>>(
      x1, W1T[1], b1f[1], gf[1], bef[1], W2T[1], b2f[1], x2, 256);
  aggr_kernel<128><<<NN / 16, 256, 0, stream>>>(offs, srclist, x2);
  mlp_mfma_kernel<256, false><<<nblk, 256, 0, stream>>>(
      x2, W1T[2], b1f[2], gf[2], bef[2], W2T[2], b2f[2], x3, 512);
  aggr_kernel<256><<<NN / 8, 256, 0, stream>>>(offs, srclist, x3);

  pool_kernel<<<NCL / 4, 256, 0, stream>>>(coffs, nodelist, x3, pooled);
  colnorm_kernel<<<128, 256, 0, stream>>>(pooled, normsq);
  normalize_kernel<<<((long)NCL * 512 + 255) / 256, 256, 0, stream>>>(pooled, normsq, (float*)d_out);
}